// Round 2
// 235.033 us; speedup vs baseline: 1.0329x; 1.0329x over previous
//
#include <hip/hip_runtime.h>

// Swin shifted-window attention, fused, bf16 MFMA (16x16x32).
// B=16 H=W=128 C=96 NH=3 d=32 WS=8 SS=4 -> L=64 tokens/window, 4096 blocks.
// R6: de-risked rewrite of R5 (which failed absmax):
//   - KEEP: swapped QK^T (S^T = mfma(K,Q)) -> P in registers, pb LDS gone;
//           kb stride 40->32 with 16B-chunk XOR swizzle; LDS 39424 B -> 4 blk/CU;
//           biasT [h][k][q] coalesced; edge-uniform mask skip.
//   - REVERT: all v_cvt_pk_bf16_f32 asm -> R4-proven f2b scalar conversion;
//             rcpf -> 1.0f/rs; attn->proj __syncthreads restored.
//   - REWRITE: P redistribution as a simple gather: dest word w pulls
//             w2[2kk+(quad>>1)][w&1] from lane (2*(quad&1)+(w>>1))*16+l16
//             (two unconditional shfls + select; lane-traced 0/21/32/47/63).
// Fragment layouts (verified on gfx950 via R4):
//   A: lane holds A[m=lane&15][k=quad*8+j]
//   B: lane holds B[k=quad*8+j][n=lane&15]
//   C/D: lane holds (row=quad*4+reg, col=lane&15)

typedef __attribute__((ext_vector_type(8))) short short8;
typedef __attribute__((ext_vector_type(4))) float f32x4;

#define XST 104   // xs row stride (bf16): 208B, 2-way banks (free)
#define VST 72    // vt row stride: 144B

// ws layout:
//   shorts [0        .. 27647]  qkv_w bf16, row-major [col][96], cols 0..95 pre-scaled
//   shorts [27648    .. 36863]  proj_w bf16, row-major [col][96]
//   bytes  73728..74879         qkv_b fp32 (288), cols 0..95 pre-scaled
//   bytes  74880..75263         proj_b fp32 (96)
//   bytes  75776..124927        biasT fp32 [3][64][64] = rel_bias transposed [h][k][q]
#define WS_QKVW 0
#define WS_PROJW 27648
#define WS_QKVB_BYTES 73728
#define WS_PROJB_BYTES 74880
#define WS_BIAST_BYTES 75776
#define WS_TOTAL_BYTES (WS_BIAST_BYTES + 3 * 64 * 64 * 4)

__device__ __forceinline__ unsigned short f2b(float f) {
    union { float f; unsigned u; } v; v.f = f;
    unsigned r = v.u + 0x7fffu + ((v.u >> 16) & 1u);   // RNE
    return (unsigned short)(r >> 16);
}

__device__ __forceinline__ unsigned pack2(float a, float b) {
    return (unsigned)f2b(a) | ((unsigned)f2b(b) << 16);   // lo=a, hi=b
}

__global__ void prep_weights(const float* __restrict__ qkv_w,
                             const float* __restrict__ qkv_b,
                             const float* __restrict__ proj_w,
                             const float* __restrict__ proj_b,
                             const float* __restrict__ rel_bias,
                             void* __restrict__ ws, int do_bias)
{
    unsigned short* wsh = (unsigned short*)ws;
    float* fqb = (float*)((char*)ws + WS_QKVB_BYTES);
    float* fpb = (float*)((char*)ws + WS_PROJB_BYTES);
    float* fbt = (float*)((char*)ws + WS_BIAST_BYTES);
    const float qs = 0.17677669529663687f;  // 1/sqrt(32)

    int idx = blockIdx.x * 256 + threadIdx.x;
    if (idx < 27648) {                       // qkv_w
        int col = idx / 96;
        float v = qkv_w[idx];
        if (col < 96) v *= qs;
        wsh[WS_QKVW + idx] = f2b(v);
    } else if (idx < 36864) {                // proj_w
        wsh[WS_PROJW + (idx - 27648)] = f2b(proj_w[idx - 27648]);
    } else if (idx < 37152) {                // qkv_b
        int col = idx - 36864;
        float v = qkv_b[col];
        if (col < 96) v *= qs;
        fqb[col] = v;
    } else if (idx < 37248) {                // proj_b
        fpb[idx - 37152] = proj_b[idx - 37152];
    } else if (do_bias && idx < 49536) {     // biasT[h][k][q] = rel_bias[h][q][k]
        int i2 = idx - 37248;
        int h = i2 >> 12;
        int rem = i2 & 4095;
        int k = rem >> 6, q = rem & 63;
        fbt[i2] = rel_bias[(h * 64 + q) * 64 + k];
    }
}

__global__ __launch_bounds__(256, 4) void swin_mfma(
    const float* __restrict__ x,
    const float* __restrict__ rel_bias,     // [h][q][k] fallback path
    const float* __restrict__ biasT,        // [h][k][q] in ws, or nullptr
    const void* __restrict__ ws,
    float* __restrict__ out)
{
    const unsigned short* wqkv  = (const unsigned short*)ws + WS_QKVW;
    const unsigned short* wproj = (const unsigned short*)ws + WS_PROJW;
    const float* wqkvb = (const float*)((const char*)ws + WS_QKVB_BYTES);
    const float* wprjb = (const float*)((const char*)ws + WS_PROJB_BYTES);

    __shared__ __align__(16) unsigned short xs[64 * XST];      // 13.0 KB: x -> Q -> attn-out
    __shared__ __align__(16) unsigned short kb[3 * 64 * 32];   // 12.0 KB: K, chunk-XOR swizzled
    __shared__ __align__(16) unsigned short vt[3 * 32 * VST];  // 13.5 KB: v transposed [d][row]
    // total 39424 B -> 4 blocks/CU

    const int t    = threadIdx.x;
    const int wv   = t >> 6;          // wave id 0..3 = q-strip owner
    const int lane = t & 63;
    const int quad = lane >> 4;
    const int l16  = lane & 15;
    const int m0   = wv * 16;

    const int blk = blockIdx.x;
    const int bb  = blk >> 8;
    const int win = blk & 255;
    const int wh  = win >> 4, ww = win & 15;

    // ---- stage x window -> bf16 LDS (rolled coords) ----
    for (int idx = t; idx < 1536; idx += 256) {
        int row = idx / 24;
        int c4  = idx - row * 24;
        int r = row >> 3, c = row & 7;
        int gh = (wh * 8 + r + 4) & 127;
        int gw = (ww * 8 + c + 4) & 127;
        float4 v = *(const float4*)&x[(((bb * 128 + gh) * 128 + gw) * 96) + c4 * 4];
        ushort4 pk;
        pk.x = f2b(v.x); pk.y = f2b(v.y); pk.z = f2b(v.z); pk.w = f2b(v.w);
        *(ushort4*)&xs[row * XST + c4 * 4] = pk;
    }
    __syncthreads();

    // ---- preload X A-frags; then xs is dead and can hold Q ----
    short8 af[4][3];
    #pragma unroll
    for (int mt = 0; mt < 4; ++mt)
        #pragma unroll
        for (int ks = 0; ks < 3; ++ks)
            af[mt][ks] = *(const short8*)&xs[(mt * 16 + l16) * XST + ks * 32 + quad * 8];
    __syncthreads();   // all waves done reading x from xs

    // ---- QKV GEMM: 64x288 = (4 m-tiles) x (18 n-tiles) x (3 k-steps) ----
    for (int nt = wv; nt < 18; nt += 4) {
        const int n0 = nt * 16;
        float bias = wqkvb[n0 + l16];
        f32x4 acc[4];
        #pragma unroll
        for (int mt = 0; mt < 4; ++mt) acc[mt] = (f32x4){bias, bias, bias, bias};
        #pragma unroll
        for (int ks = 0; ks < 3; ++ks) {
            short8 bf = *(const short8*)&wqkv[(n0 + l16) * 96 + ks * 32 + quad * 8];
            #pragma unroll
            for (int mt = 0; mt < 4; ++mt)
                acc[mt] = __builtin_amdgcn_mfma_f32_16x16x32_bf16(af[mt][ks], bf, acc[mt], 0, 0, 0);
        }
        if (nt < 6) {            // Q (pre-scaled) -> xs[row][col]  (R4-identical)
            int col = n0 + l16;
            #pragma unroll
            for (int mt = 0; mt < 4; ++mt)
                #pragma unroll
                for (int r = 0; r < 4; ++r)
                    xs[(mt * 16 + quad * 4 + r) * XST + col] = f2b(acc[mt][r]);
        } else if (nt < 12) {    // K row-major, stride 32, 16B-chunk XOR swizzle
            int col = n0 - 96 + l16; int hh = col >> 5; int d = col & 31;
            int dch = d >> 3, dlo = d & 7;
            #pragma unroll
            for (int mt = 0; mt < 4; ++mt)
                #pragma unroll
                for (int r = 0; r < 4; ++r) {
                    int row = hh * 64 + mt * 16 + quad * 4 + r;
                    int c = ((dch ^ ((row >> 1) & 3)) << 3) + dlo;
                    kb[row * 32 + c] = f2b(acc[mt][r]);
                }
        } else {                 // V transposed [d][row], packed 8B stores (R4-identical)
            int col = n0 - 192 + l16; int hh = col >> 5; int d = col & 31;
            #pragma unroll
            for (int mt = 0; mt < 4; ++mt) {
                ushort4 pk;
                pk.x = f2b(acc[mt][0]); pk.y = f2b(acc[mt][1]);
                pk.z = f2b(acc[mt][2]); pk.w = f2b(acc[mt][3]);
                *(ushort4*)&vt[(hh * 32 + d) * VST + mt * 16 + quad * 4] = pk;
            }
        }
    }
    __syncthreads();

    // ---- attention, swapped QK^T: lane holds P row q=m0+l16, k=nt*16+quad*4+r ----
    {
        const bool bh = (wh == 15), bw = (ww == 15);
        const bool edge = bh || bw;
        const int qtok = m0 + l16;
        const int qrr = bh ? (((qtok >> 3) < 4) ? 1 : 2) : 0;
        const int qcc = bw ? (((qtok & 7) < 4) ? 1 : 2) : 0;

        for (int h = 0; h < 3; ++h) {
            // K as A-operand, Q as B-operand (reads identical to R4; only arg order swaps)
            short8 qa = *(const short8*)&xs[(m0 + l16) * XST + h * 32 + quad * 8];
            f32x4 s[4];
            #pragma unroll
            for (int nt = 0; nt < 4; ++nt) {
                int rowk = h * 64 + nt * 16 + l16;
                short8 kf = *(const short8*)&kb[rowk * 32 + ((quad ^ ((rowk >> 1) & 3)) << 3)];
                f32x4 z = (f32x4){0.f, 0.f, 0.f, 0.f};
                s[nt] = __builtin_amdgcn_mfma_f32_16x16x32_bf16(kf, qa, z, 0, 0, 0);
            }
            float p[4][4];
            float rs = 0.f;
            #pragma unroll
            for (int nt = 0; nt < 4; ++nt) {
                #pragma unroll
                for (int r = 0; r < 4; ++r) {
                    int ktok = nt * 16 + quad * 4 + r;
                    float bv = biasT ? biasT[(h * 64 + ktok) * 64 + qtok]
                                     : rel_bias[(h * 64 + qtok) * 64 + ktok];
                    float arg = s[nt][r] + bv;
                    if (edge) {
                        int krr = bh ? (((ktok >> 3) < 4) ? 1 : 2) : 0;
                        int kcc = bw ? (((ktok & 7) < 4) ? 1 : 2) : 0;
                        if (krr != qrr || kcc != qcc) arg -= 100.f;
                    }
                    float e = __expf(arg);     // unmasked |s|<~3 -> no overflow
                    p[nt][r] = e;
                    rs += e;
                }
            }
            rs += __shfl_xor(rs, 16);          // full row-sum across the 4 quads
            rs += __shfl_xor(rs, 32);
            float rinv = 1.0f / rs;

            // normalize + pack: w2[nt][i] = bf16x2(p[nt][2i], p[nt][2i+1])
            unsigned w2[4][2];
            #pragma unroll
            for (int nt = 0; nt < 4; ++nt) {
                w2[nt][0] = pack2(p[nt][0] * rinv, p[nt][1] * rinv);
                w2[nt][1] = pack2(p[nt][2] * rinv, p[nt][3] * rinv);
            }
            // gather C-layout -> A-frag:  pa[kk][j] = P[q=m0+l16][k=kk*32+quad*8+j]
            //   dest word w (j=2w,2w+1): source lane (2*(quad&1)+(w>>1))*16 + l16,
            //   value w2[2kk + (quad>>1)][w&1]
            short8 pa[2];
            #pragma unroll
            for (int kk = 0; kk < 2; ++kk) {
                union { unsigned u[4]; short8 s8; } uw;
                #pragma unroll
                for (int w = 0; w < 4; ++w) {
                    int src = (2 * (quad & 1) + (w >> 1)) * 16 + l16;
                    int lo = __shfl((int)w2[2 * kk][w & 1], src);
                    int hi = __shfl((int)w2[2 * kk + 1][w & 1], src);
                    uw.u[w] = (quad & 2) ? (unsigned)hi : (unsigned)lo;
                }
                pa[kk] = uw.s8;
            }

            f32x4 o0 = (f32x4){0.f, 0.f, 0.f, 0.f};
            f32x4 o1 = o0;
            #pragma unroll
            for (int kk = 0; kk < 2; ++kk) {
                short8 v0 = *(const short8*)&vt[(h * 32 + l16) * VST + kk * 32 + quad * 8];
                short8 v1 = *(const short8*)&vt[(h * 32 + 16 + l16) * VST + kk * 32 + quad * 8];
                o0 = __builtin_amdgcn_mfma_f32_16x16x32_bf16(pa[kk], v0, o0, 0, 0, 0);
                o1 = __builtin_amdgcn_mfma_f32_16x16x32_bf16(pa[kk], v1, o1, 0, 0, 0);
            }
            // attn-out -> xs (rows wave-private; P already normalized)
            #pragma unroll
            for (int r = 0; r < 4; ++r) {
                xs[(m0 + quad * 4 + r) * XST + h * 32 + l16]      = f2b(o0[r]);
                xs[(m0 + quad * 4 + r) * XST + h * 32 + 16 + l16] = f2b(o1[r]);
            }
        }
    }
    __syncthreads();

    // ---- proj GEMM: 64x96, wave wv does m-tile wv x (6 n-tiles) x (3 k-steps) ----
    {
        short8 pja[3];
        #pragma unroll
        for (int ks = 0; ks < 3; ++ks)
            pja[ks] = *(const short8*)&xs[(m0 + l16) * XST + ks * 32 + quad * 8];

        int rowbase[4];
        #pragma unroll
        for (int r = 0; r < 4; ++r) {
            int tok = m0 + quad * 4 + r;
            int tr = tok >> 3, tc = tok & 7;
            int gh = (wh * 8 + tr + 4) & 127;
            int gw = (ww * 8 + tc + 4) & 127;
            rowbase[r] = ((bb * 128 + gh) * 128 + gw) * 96;
        }
        #pragma unroll
        for (int nt = 0; nt < 6; ++nt) {
            const int n0 = nt * 16;
            float bias = wprjb[n0 + l16];
            f32x4 acc = (f32x4){bias, bias, bias, bias};
            #pragma unroll
            for (int ks = 0; ks < 3; ++ks) {
                short8 bf = *(const short8*)&wproj[(n0 + l16) * 96 + ks * 32 + quad * 8];
                acc = __builtin_amdgcn_mfma_f32_16x16x32_bf16(pja[ks], bf, acc, 0, 0, 0);
            }
            #pragma unroll
            for (int r = 0; r < 4; ++r)
                out[rowbase[r] + n0 + l16] = acc[r];
        }
    }
}

extern "C" void kernel_launch(void* const* d_in, const int* in_sizes, int n_in,
                              void* d_out, int out_size, void* d_ws, size_t ws_size,
                              hipStream_t stream) {
    const float* x        = (const float*)d_in[0];
    const float* qkv_w    = (const float*)d_in[1];
    const float* qkv_b    = (const float*)d_in[2];
    const float* proj_w   = (const float*)d_in[3];
    const float* proj_b   = (const float*)d_in[4];
    const float* rel_bias = (const float*)d_in[5];
    float* out = (float*)d_out;

    const float* biasT = nullptr;
    if (ws_size >= (size_t)WS_TOTAL_BYTES)
        biasT = (const float*)((const char*)d_ws + WS_BIAST_BYTES);

    hipLaunchKernelGGL(prep_weights, dim3(194), dim3(256), 0, stream,
                       qkv_w, qkv_b, proj_w, proj_b, rel_bias, d_ws, biasT ? 1 : 0);
    hipLaunchKernelGGL(swin_mfma, dim3(4096), dim3(256), 0, stream,
                       x, rel_bias, biasT, (const void*)d_ws, out);
}